// Round 1
// baseline (1757.861 us; speedup 1.0000x reference)
//
#include <hip/hip_runtime.h>
#include <hip/hip_bf16.h>

#define EPS 1e-5f

// Problem constants (from setup_inputs)
constexpr int B   = 32;
constexpr int C   = 256;
constexpr int O   = 256;
constexpr int NZ  = 7 * 7;     // 49
constexpr int NX  = 31 * 31;   // 961
constexpr int C3  = 3 * C;     // 768
constexpr int BCHUNK = 8;      // batches per self-attention score chunk

// ---------------------------------------------------------------------------
// Generic tiled fp32 GEMM:
//   Cm[b][i][j] = act( sum_k A[b][i][k] * B[b][k][j] )
// AT: A element [i][k] stored at A[k*lda + i]   (else A[i*lda + k])
// BT: B element [k][j] stored at B[j*ldb + k]   (else B[k*ldb + j])
// ACT: 0 = none, 1 = +bias, 2 = +bias, BN, ReLU
// 64x64 tile, K-step 16, 256 threads, 4x4 microtile.
// ---------------------------------------------------------------------------
template <bool AT, bool BT, int ACT>
__global__ __launch_bounds__(256)
void gemm_kernel(const float* __restrict__ Abase, long sA, int lda,
                 const float* __restrict__ Bbase, long sB, int ldb,
                 float* __restrict__ Cbase, long sC, int ldc,
                 int M, int N, int K,
                 const float* __restrict__ bias,
                 const float* __restrict__ gamma,
                 const float* __restrict__ beta,
                 const float* __restrict__ mean,
                 const float* __restrict__ var)
{
    const int b = blockIdx.z;
    const float* A  = Abase + (long)b * sA;
    const float* Bm = Bbase + (long)b * sB;
    float*       Cm = Cbase + (long)b * sC;

    const int i0 = blockIdx.y * 64;
    const int j0 = blockIdx.x * 64;

    __shared__ float As[16][68];  // [kk][ii], padded: 68*4B = 16B-aligned rows
    __shared__ float Bs[16][68];  // [kk][jj]

    const int tid = threadIdx.x;
    const int tx  = tid & 15;   // j group
    const int ty  = tid >> 4;   // i group

    float acc[4][4] = {};

    for (int k0 = 0; k0 < K; k0 += 16) {
        // ---- load A tile ----
        if (AT) {
            // As[kk][ii] = A[(k0+kk)*lda + (i0+ii)]  (contiguous in ii)
            #pragma unroll
            for (int e = 0; e < 4; ++e) {
                int idx = tid + e * 256;
                int kk = idx >> 6, ii = idx & 63;
                int gi = i0 + ii, gk = k0 + kk;
                As[kk][ii] = (gi < M && gk < K) ? A[(long)gk * lda + gi] : 0.f;
            }
        } else {
            // As[kk][ii] = A[(i0+ii)*lda + (k0+kk)]  (contiguous in kk)
            #pragma unroll
            for (int e = 0; e < 4; ++e) {
                int idx = tid + e * 256;
                int ii = idx >> 4, kk = idx & 15;
                int gi = i0 + ii, gk = k0 + kk;
                As[kk][ii] = (gi < M && gk < K) ? A[(long)gi * lda + gk] : 0.f;
            }
        }
        // ---- load B tile ----
        if (!BT) {
            #pragma unroll
            for (int e = 0; e < 4; ++e) {
                int idx = tid + e * 256;
                int kk = idx >> 6, jj = idx & 63;
                int gk = k0 + kk, gj = j0 + jj;
                Bs[kk][jj] = (gk < K && gj < N) ? Bm[(long)gk * ldb + gj] : 0.f;
            }
        } else {
            #pragma unroll
            for (int e = 0; e < 4; ++e) {
                int idx = tid + e * 256;
                int jj = idx >> 4, kk = idx & 15;
                int gk = k0 + kk, gj = j0 + jj;
                Bs[kk][jj] = (gk < K && gj < N) ? Bm[(long)gj * ldb + gk] : 0.f;
            }
        }
        __syncthreads();

        #pragma unroll
        for (int kk = 0; kk < 16; ++kk) {
            float av[4], bv[4];
            #pragma unroll
            for (int u = 0; u < 4; ++u) av[u] = As[kk][ty * 4 + u];
            #pragma unroll
            for (int u = 0; u < 4; ++u) bv[u] = Bs[kk][tx * 4 + u];
            #pragma unroll
            for (int i = 0; i < 4; ++i)
                #pragma unroll
                for (int j = 0; j < 4; ++j)
                    acc[i][j] = fmaf(av[i], bv[j], acc[i][j]);
        }
        __syncthreads();
    }

    // ---- epilogue ----
    #pragma unroll
    for (int i = 0; i < 4; ++i) {
        int gi = i0 + ty * 4 + i;
        if (gi >= M) continue;
        float add = 0.f, sc = 1.f, sh = 0.f;
        if (ACT >= 1) add = bias[gi];
        if (ACT == 2) {
            float inv = 1.0f / sqrtf(var[gi] + EPS);
            sc = gamma[gi] * inv;
            sh = beta[gi] - mean[gi] * sc;
        }
        #pragma unroll
        for (int j = 0; j < 4; ++j) {
            int gj = j0 + tx * 4 + j;
            if (gj >= N) continue;
            float v = acc[i][j] + add;
            if (ACT == 2) v = fmaxf(v * sc + sh, 0.f);
            Cm[(long)gi * ldc + gj] = v;
        }
    }
}

// ---------------------------------------------------------------------------
// Fused dual 1x1 conv: shares the X tile between two weight matrices.
//   Y1[b][o][n] = W1[o,:]·X[b,:,n] + bias1[o]
//   Y2[b][o][n] = relu(bn(W2[o,:]·X[b,:,n] + bias2[o]))
// M = K = C = 256 fixed.
// ---------------------------------------------------------------------------
__global__ __launch_bounds__(256)
void dualconv_kernel(const float* __restrict__ W1, const float* __restrict__ bias1,
                     const float* __restrict__ W2, const float* __restrict__ bias2,
                     const float* __restrict__ gamma, const float* __restrict__ beta,
                     const float* __restrict__ mean,  const float* __restrict__ var,
                     const float* __restrict__ Xb, long sX,
                     float* __restrict__ Y1, long sY1, int ldy1,
                     float* __restrict__ Y2, long sY2, int ldy2,
                     int N)
{
    const int b = blockIdx.z;
    const float* X = Xb + (long)b * sX;
    float* y1 = Y1 + (long)b * sY1;
    float* y2 = Y2 + (long)b * sY2;

    const int i0 = blockIdx.y * 64;
    const int j0 = blockIdx.x * 64;

    __shared__ float A1s[16][68];
    __shared__ float A2s[16][68];
    __shared__ float Bs[16][68];

    const int tid = threadIdx.x;
    const int tx  = tid & 15;
    const int ty  = tid >> 4;

    float acc1[4][4] = {}, acc2[4][4] = {};

    for (int k0 = 0; k0 < C; k0 += 16) {
        #pragma unroll
        for (int e = 0; e < 4; ++e) {
            int idx = tid + e * 256;
            int ii = idx >> 4, kk = idx & 15;
            A1s[kk][ii] = W1[(i0 + ii) * C + k0 + kk];
            A2s[kk][ii] = W2[(i0 + ii) * C + k0 + kk];
        }
        #pragma unroll
        for (int e = 0; e < 4; ++e) {
            int idx = tid + e * 256;
            int kk = idx >> 6, jj = idx & 63;
            int gj = j0 + jj;
            Bs[kk][jj] = (gj < N) ? X[(long)(k0 + kk) * N + gj] : 0.f;
        }
        __syncthreads();

        #pragma unroll
        for (int kk = 0; kk < 16; ++kk) {
            float a1[4], a2[4], bv[4];
            #pragma unroll
            for (int u = 0; u < 4; ++u) a1[u] = A1s[kk][ty * 4 + u];
            #pragma unroll
            for (int u = 0; u < 4; ++u) a2[u] = A2s[kk][ty * 4 + u];
            #pragma unroll
            for (int u = 0; u < 4; ++u) bv[u] = Bs[kk][tx * 4 + u];
            #pragma unroll
            for (int i = 0; i < 4; ++i) {
                #pragma unroll
                for (int j = 0; j < 4; ++j) {
                    acc1[i][j] = fmaf(a1[i], bv[j], acc1[i][j]);
                    acc2[i][j] = fmaf(a2[i], bv[j], acc2[i][j]);
                }
            }
        }
        __syncthreads();
    }

    #pragma unroll
    for (int i = 0; i < 4; ++i) {
        int gi = i0 + ty * 4 + i;
        float ad1 = bias1[gi];
        float ad2 = bias2[gi];
        float inv = 1.0f / sqrtf(var[gi] + EPS);
        float sc  = gamma[gi] * inv;
        float sh  = beta[gi] - mean[gi] * sc;
        #pragma unroll
        for (int j = 0; j < 4; ++j) {
            int gj = j0 + tx * 4 + j;
            if (gj < N) {
                y1[(long)gi * ldy1 + gj] = acc1[i][j] + ad1;
                float v = (acc2[i][j] + ad2) * sc + sh;
                y2[(long)gi * ldy2 + gj] = fmaxf(v, 0.f);
            }
        }
    }
}

// ---------------------------------------------------------------------------
// Row softmax over last dim. One block per row. Works with blockDim 64 or 256.
// ---------------------------------------------------------------------------
__global__ void softmax_kernel(float* __restrict__ S, int M, long ld)
{
    float* p = S + (long)blockIdx.x * ld;
    const int tid = threadIdx.x;
    const int nw  = blockDim.x >> 6;
    __shared__ float redm[8], reds[8];

    float mx = -3.0e38f;
    for (int m = tid; m < M; m += blockDim.x) mx = fmaxf(mx, p[m]);
    #pragma unroll
    for (int o = 32; o; o >>= 1) mx = fmaxf(mx, __shfl_xor(mx, o, 64));
    if ((tid & 63) == 0) redm[tid >> 6] = mx;
    __syncthreads();
    if (nw > 1) {
        mx = redm[0];
        for (int w = 1; w < nw; ++w) mx = fmaxf(mx, redm[w]);
    }

    float sum = 0.f;
    for (int m = tid; m < M; m += blockDim.x) {
        float e = __expf(p[m] - mx);
        p[m] = e;
        sum += e;
    }
    #pragma unroll
    for (int o = 32; o; o >>= 1) sum += __shfl_xor(sum, o, 64);
    if ((tid & 63) == 0) reds[tid >> 6] = sum;
    __syncthreads();
    if (nw > 1) {
        sum = reds[0];
        for (int w = 1; w < nw; ++w) sum += reds[w];
    }

    float inv = 1.f / sum;
    for (int m = tid; m < M; m += blockDim.x) p[m] *= inv;
}

// ---------------------------------------------------------------------------
extern "C" void kernel_launch(void* const* d_in, const int* in_sizes, int n_in,
                              void* d_out, int out_size, void* d_ws, size_t ws_size,
                              hipStream_t stream)
{
    const float* zf       = (const float*)d_in[0];
    const float* xf       = (const float*)d_in[1];
    const float* Wq       = (const float*)d_in[2];
    const float* bq       = (const float*)d_in[3];
    const float* Ws       = (const float*)d_in[4];
    const float* bs       = (const float*)d_in[5];
    const float* Wg       = (const float*)d_in[6];
    const float* bg       = (const float*)d_in[7];
    const float* g_gamma  = (const float*)d_in[8];
    const float* g_beta   = (const float*)d_in[9];
    const float* g_mean   = (const float*)d_in[10];
    const float* g_var    = (const float*)d_in[11];
    const float* Wfi      = (const float*)d_in[12];
    const float* bfi      = (const float*)d_in[13];
    const float* fi_gamma = (const float*)d_in[14];
    const float* fi_beta  = (const float*)d_in[15];
    const float* fi_mean  = (const float*)d_in[16];
    const float* fi_var   = (const float*)d_in[17];
    float* out = (float*)d_out;

    // ---- workspace layout (floats) ----
    float* ws = (float*)d_ws;
    float* concat   = ws;                                   // [B][3C][NX]
    float* xf_trans = concat   + (long)B * C3 * NX;         // [B][C][NX]
    float* zf_trans = xf_trans + (long)B * C  * NX;         // [B][C][NZ]
    float* zf_g     = zf_trans + (long)B * C  * NZ;         // [B][C][NZ]
    float* S_sim    = zf_g     + (long)B * C  * NZ;         // [B][NX][NZ]
    float* S_chunk  = S_sim    + (long)B * NX * NZ;         // [BCHUNK][NX][NX]

    float* xf_gate  = concat + (long)2 * C * NX;            // section 2 of concat
    float* emb      = concat;                               // section 0
    float* self_emb = concat + (long)C * NX;                // section 1

    // 1) xf convs: xf_trans = Wq*xf + bq ; xf_gate = relu(bn(Wg*xf + bg))
    dualconv_kernel<<<dim3(16, 4, B), 256, 0, stream>>>(
        Wq, bq, Wg, bg, g_gamma, g_beta, g_mean, g_var,
        xf, (long)C * NX,
        xf_trans, (long)C * NX, NX,
        xf_gate, (long)C3 * NX, NX,
        NX);

    // 2) zf convs: zf_trans = Ws*zf + bs ; zf_g = relu(bn(Wg*zf + bg))
    dualconv_kernel<<<dim3(1, 4, B), 256, 0, stream>>>(
        Ws, bs, Wg, bg, g_gamma, g_beta, g_mean, g_var,
        zf, (long)C * NZ,
        zf_trans, (long)C * NZ, NZ,
        zf_g, (long)C * NZ, NZ,
        NZ);

    // 3) similar scores: S_sim[b][n][m] = sum_c xf_trans[b,c,n] * zf_trans[b,c,m]
    gemm_kernel<true, false, 0><<<dim3(1, 16, B), 256, 0, stream>>>(
        xf_trans, (long)C * NX, NX,
        zf_trans, (long)C * NZ, NZ,
        S_sim, (long)NX * NZ, NZ,
        NX, NZ, C, nullptr, nullptr, nullptr, nullptr, nullptr);

    // 4) softmax over m (rows of 49)
    softmax_kernel<<<dim3(B * NX), 64, 0, stream>>>(S_sim, NZ, NZ);

    // 5) emb[b][c][n] = sum_m zf_g[b,c,m] * S_sim[b,n,m]
    gemm_kernel<false, true, 0><<<dim3(16, 4, B), 256, 0, stream>>>(
        zf_g, (long)C * NZ, NZ,
        S_sim, (long)NX * NZ, NZ,
        emb, (long)C3 * NX, NX,
        C, NX, NZ, nullptr, nullptr, nullptr, nullptr, nullptr);

    // 6) self-attention, chunked over batches
    for (int ch = 0; ch < B / BCHUNK; ++ch) {
        const float* xt = xf_trans + (long)ch * BCHUNK * C * NX;
        const float* xg = xf_gate + (long)ch * BCHUNK * C3 * NX;
        float* se = self_emb + (long)ch * BCHUNK * C3 * NX;

        // scores: S[b][n][m] = sum_c xt[b,c,n] * xt[b,c,m]
        gemm_kernel<true, false, 0><<<dim3(16, 16, BCHUNK), 256, 0, stream>>>(
            xt, (long)C * NX, NX,
            xt, (long)C * NX, NX,
            S_chunk, (long)NX * NX, NX,
            NX, NX, C, nullptr, nullptr, nullptr, nullptr, nullptr);

        softmax_kernel<<<dim3(BCHUNK * NX), 256, 0, stream>>>(S_chunk, NX, NX);

        // self_emb[b][c][n] = sum_m xf_gate[b,c,m] * P[b,n,m]
        gemm_kernel<false, true, 0><<<dim3(16, 4, BCHUNK), 256, 0, stream>>>(
            xg, (long)C3 * NX, NX,
            S_chunk, (long)NX * NX, NX,
            se, (long)C3 * NX, NX,
            C, NX, NX, nullptr, nullptr, nullptr, nullptr, nullptr);
    }

    // 7) final conv: out = relu(bn(Wfi*concat + bfi))
    gemm_kernel<false, false, 2><<<dim3(16, 4, B), 256, 0, stream>>>(
        Wfi, 0L, C3,
        concat, (long)C3 * NX, NX,
        out, (long)O * NX, NX,
        O, NX, C3, bfi, fi_gamma, fi_beta, fi_mean, fi_var);
}

// Round 2
// 504.517 us; speedup vs baseline: 3.4842x; 3.4842x over previous
//
#include <hip/hip_runtime.h>
#include <hip/hip_bf16.h>

#define EPS 1e-5f

constexpr int B    = 32;
constexpr int C    = 256;
constexpr int O    = 256;
constexpr int NZ   = 49;
constexpr int NX   = 961;
constexpr int NXP  = 1024;   // padded NX (rows, tiles of 128)
constexpr int NZP  = 128;    // padded NZ rows
constexpr int C3   = 768;
constexpr int BCH  = 8;      // self-attn batch chunk

typedef short  bf16x8 __attribute__((ext_vector_type(8)));
typedef float  f32x4  __attribute__((ext_vector_type(4)));

__device__ inline ushort f2bf(float f) {
    union { float f; uint u; } v; v.f = f;
    uint r = v.u + 0x7fffu + ((v.u >> 16) & 1u);   // round-to-nearest-even
    return (ushort)(r >> 16);
}

// ---------------------------------------------------------------------------
// NT MFMA GEMM: C[b][i][j] = act( sum_k A'[b][i][k] * B'[b][j][k] )
// A' [M][K] bf16 row-major (k contiguous), B' [N][K] bf16 row-major.
// Tile 128x128, BK=32, 256 threads (4 waves, 2x2), 16x16x32 bf16 MFMA.
// Staging: global_load_lds width=16, linear LDS dest, involutive XOR-swizzled
// global source; reads apply the same swizzle (byte ^= (row&6)<<3).
// ACT: 0 none, 1 +bias, 2 +bias,BN,ReLU.  BIAS_COL: params indexed by j (else i).
// No bounds checks in staging: all operand buffers padded to tile multiples.
// ---------------------------------------------------------------------------
template<int ACT, bool BIAS_COL, bool OUT_BF16>
__global__ __launch_bounds__(256)
void mfma_nt(const ushort* __restrict__ Abase, long sA, int lda,
             const ushort* __restrict__ Bbase, long sB, int ldb,
             void* __restrict__ Cbase, long sC, int ldc, int Nstore,
             int K,
             const float* __restrict__ bias,
             const float* __restrict__ gamma, const float* __restrict__ beta,
             const float* __restrict__ mean,  const float* __restrict__ varr)
{
    __shared__ ushort As[4096];   // 128 rows x 32 k (8 KB), swizzled
    __shared__ ushort Bs[4096];

    const int b   = blockIdx.z;
    const ushort* A  = Abase + (long)b * sA;
    const ushort* Bm = Bbase + (long)b * sB;
    const int i0 = blockIdx.y * 128;
    const int j0 = blockIdx.x * 128;

    const int tid  = threadIdx.x;
    const int lane = tid & 63;
    const int wid  = tid >> 6;
    const int wrow = wid >> 1, wcol = wid & 1;

    // ---- staging source offsets (pre-swizzled global source, linear LDS dest)
    // slot s (16B): row = s>>2, lkq = s&3; source kq = lkq ^ ((row>>1)&3)
    const int s0 = wid * 128 + lane;    // instr e=0
    const int s1 = s0 + 64;             // instr e=1
    auto soff = [](int s, int ld) {
        int row = s >> 2;
        int kq  = (s & 3) ^ ((s >> 3) & 3);
        return (long)row * ld + kq * 8;
    };
    const ushort* gA0 = A  + (long)i0 * lda + soff(s0, lda);
    const ushort* gA1 = A  + (long)i0 * lda + soff(s1, lda);
    const ushort* gB0 = Bm + (long)j0 * ldb + soff(s0, ldb);
    const ushort* gB1 = Bm + (long)j0 * ldb + soff(s1, ldb);

    ushort* lA0 = As + wid * 1024;        // (wid*2+0)*512 ushorts, wave-uniform
    ushort* lA1 = As + wid * 1024 + 512;
    ushort* lB0 = Bs + wid * 1024;
    ushort* lB1 = Bs + wid * 1024 + 512;

    // ---- fragment read offsets (fixed across k-steps; swizzled, ushort units)
    const int rl = lane & 15, kq = lane >> 4;
    int aoff[4], boff[4];
    #pragma unroll
    for (int f = 0; f < 4; ++f) {
        int ra = wrow * 64 + f * 16 + rl;
        int ba = (ra * 64 + kq * 16) ^ ((ra & 6) << 3);
        aoff[f] = ba >> 1;
        int rb = wcol * 64 + f * 16 + rl;
        int bb = (rb * 64 + kq * 16) ^ ((rb & 6) << 3);
        boff[f] = bb >> 1;
    }

    f32x4 acc[4][4];
    #pragma unroll
    for (int i = 0; i < 4; ++i)
        #pragma unroll
        for (int j = 0; j < 4; ++j)
            acc[i][j] = (f32x4){0.f, 0.f, 0.f, 0.f};

    for (int k0 = 0; k0 < K; k0 += 32) {
        __builtin_amdgcn_global_load_lds((const __attribute__((address_space(1))) void*)gA0,
                                         (__attribute__((address_space(3))) void*)lA0, 16, 0, 0);
        __builtin_amdgcn_global_load_lds((const __attribute__((address_space(1))) void*)gA1,
                                         (__attribute__((address_space(3))) void*)lA1, 16, 0, 0);
        __builtin_amdgcn_global_load_lds((const __attribute__((address_space(1))) void*)gB0,
                                         (__attribute__((address_space(3))) void*)lB0, 16, 0, 0);
        __builtin_amdgcn_global_load_lds((const __attribute__((address_space(1))) void*)gB1,
                                         (__attribute__((address_space(3))) void*)lB1, 16, 0, 0);
        gA0 += 32; gA1 += 32; gB0 += 32; gB1 += 32;
        __syncthreads();

        bf16x8 av[4], bv[4];
        #pragma unroll
        for (int f = 0; f < 4; ++f) av[f] = *(const bf16x8*)(As + aoff[f]);
        #pragma unroll
        for (int f = 0; f < 4; ++f) bv[f] = *(const bf16x8*)(Bs + boff[f]);

        #pragma unroll
        for (int i = 0; i < 4; ++i)
            #pragma unroll
            for (int j = 0; j < 4; ++j)
                acc[i][j] = __builtin_amdgcn_mfma_f32_16x16x32_bf16(av[i], bv[j], acc[i][j], 0, 0, 0);
        __syncthreads();
    }

    // ---- epilogue: D frag (row=(lane>>4)*4+r, col=lane&15) [m89-verified] ----
    const int jb = j0 + wcol * 64 + rl;
    const int ib = i0 + wrow * 64 + kq * 4;

    ushort* Cb16 = (ushort*)Cbase + (long)b * sC;
    float*  Cb32 = (float*)Cbase + (long)b * sC;

    #pragma unroll
    for (int fj = 0; fj < 4; ++fj) {
        int gj = jb + fj * 16;
        if (gj >= Nstore) continue;
        float sc = 1.f, sh = 0.f;
        if (ACT >= 1 && BIAS_COL) {
            float add = bias[gj];
            if (ACT == 2) {
                float inv = rsqrtf(varr[gj] + EPS);
                sc = gamma[gj] * inv;
                sh = (add - mean[gj]) * sc + beta[gj];
            } else {
                sh = add;
            }
        }
        #pragma unroll
        for (int fi = 0; fi < 4; ++fi) {
            #pragma unroll
            for (int r = 0; r < 4; ++r) {
                int gi = ib + fi * 16 + r;
                float v = acc[fi][fj][r];
                if (ACT >= 1) {
                    if (BIAS_COL) {
                        v = v * sc + sh;
                        if (ACT == 2) v = fmaxf(v, 0.f);
                    } else {
                        float add = bias[gi];
                        if (ACT == 2) {
                            float inv = rsqrtf(varr[gi] + EPS);
                            float s2 = gamma[gi] * inv;
                            v = v * s2 + (add - mean[gi]) * s2 + beta[gi];
                            v = fmaxf(v, 0.f);
                        } else {
                            v += add;
                        }
                    }
                }
                long off = (long)gi * ldc + gj;
                if (OUT_BF16) Cb16[off] = f2bf(v);
                else          Cb32[off] = v;
            }
        }
    }
}

// ---------------------------------------------------------------------------
// fp32 [Cc][Nsrc] -> bf16 [Npad][Cc] transpose+convert (pad rows zeroed)
// ---------------------------------------------------------------------------
__global__ __launch_bounds__(256)
void transpose_cvt(const float* __restrict__ src, ushort* __restrict__ dst,
                   int Cc, int Nsrc, int Npad)
{
    const int bz = blockIdx.z;
    src += (long)bz * Cc * Nsrc;
    dst += (long)bz * Npad * Cc;
    const int c0 = blockIdx.x * 32, n0 = blockIdx.y * 32;
    __shared__ float t[32][33];
    const int lx = threadIdx.x & 31, ly = threadIdx.x >> 5;
    #pragma unroll
    for (int r = 0; r < 32; r += 8) {
        int n = n0 + lx;
        t[ly + r][lx] = (n < Nsrc) ? src[(long)(c0 + ly + r) * Nsrc + n] : 0.f;
    }
    __syncthreads();
    #pragma unroll
    for (int r = 0; r < 32; r += 8) {
        int n = n0 + ly + r;
        if (n < Npad) dst[(long)n * Cc + c0 + lx] = f2bf(t[lx][ly + r]);
    }
}

__global__ void cvt_bf(const float* __restrict__ src, ushort* __restrict__ dst, int n)
{
    int i = blockIdx.x * 256 + threadIdx.x;
    if (i < n) dst[i] = f2bf(src[i]);
}

// ---------------------------------------------------------------------------
// softmax over 961 valid cols of a [1024]-wide fp32 row -> bf16 row (pad -> 0)
// grid (961, chunk_batches), 256 threads
// ---------------------------------------------------------------------------
__global__ __launch_bounds__(256)
void softmax_self(const float* __restrict__ S, ushort* __restrict__ P)
{
    const long row = (long)blockIdx.y * 1024 + blockIdx.x;
    const float* s = S + row * 1024;
    ushort* p = P + row * 1024;
    const int tid = threadIdx.x;
    __shared__ float redm[4], reds[4];

    float mx = -3.0e38f;
    for (int m = tid; m < NX; m += 256) mx = fmaxf(mx, s[m]);
    #pragma unroll
    for (int o = 32; o; o >>= 1) mx = fmaxf(mx, __shfl_xor(mx, o, 64));
    if ((tid & 63) == 0) redm[tid >> 6] = mx;
    __syncthreads();
    mx = fmaxf(fmaxf(redm[0], redm[1]), fmaxf(redm[2], redm[3]));

    float sum = 0.f;
    for (int m = tid; m < NX; m += 256) sum += __expf(s[m] - mx);
    #pragma unroll
    for (int o = 32; o; o >>= 1) sum += __shfl_xor(sum, o, 64);
    if ((tid & 63) == 0) reds[tid >> 6] = sum;
    __syncthreads();
    sum = reds[0] + reds[1] + reds[2] + reds[3];
    float inv = 1.f / sum;

    for (int m = tid; m < 1024; m += 256) {
        float v = (m < NX) ? __expf(s[m] - mx) * inv : 0.f;
        p[m] = f2bf(v);
    }
}

// softmax over 49 cols (ld 128 fp32) -> bf16 row of 64 (pad -> 0). 64 threads.
__global__ void softmax_sim(const float* __restrict__ S, ushort* __restrict__ P)
{
    const long row = (long)blockIdx.y * 1024 + blockIdx.x;
    const float* s = S + row * 128;
    ushort* p = P + row * 64;
    const int t = threadIdx.x;
    float v = (t < NZ) ? s[t] : -3.0e38f;
    float mx = v;
    #pragma unroll
    for (int o = 32; o; o >>= 1) mx = fmaxf(mx, __shfl_xor(mx, o, 64));
    float e = (t < NZ) ? __expf(v - mx) : 0.f;
    float sum = e;
    #pragma unroll
    for (int o = 32; o; o >>= 1) sum += __shfl_xor(sum, o, 64);
    p[t] = f2bf(e / sum);
}

// ---------------------------------------------------------------------------
extern "C" void kernel_launch(void* const* d_in, const int* in_sizes, int n_in,
                              void* d_out, int out_size, void* d_ws, size_t ws_size,
                              hipStream_t stream)
{
    const float* zf       = (const float*)d_in[0];
    const float* xf       = (const float*)d_in[1];
    const float* Wq       = (const float*)d_in[2];
    const float* bq       = (const float*)d_in[3];
    const float* Ws       = (const float*)d_in[4];
    const float* bs       = (const float*)d_in[5];
    const float* Wg       = (const float*)d_in[6];
    const float* bg       = (const float*)d_in[7];
    const float* g_gamma  = (const float*)d_in[8];
    const float* g_beta   = (const float*)d_in[9];
    const float* g_mean   = (const float*)d_in[10];
    const float* g_var    = (const float*)d_in[11];
    const float* Wfi      = (const float*)d_in[12];
    const float* bfi      = (const float*)d_in[13];
    const float* fi_gamma = (const float*)d_in[14];
    const float* fi_beta  = (const float*)d_in[15];
    const float* fi_mean  = (const float*)d_in[16];
    const float* fi_var   = (const float*)d_in[17];
    float* out = (float*)d_out;

    // ---- workspace layout (persistent | union{sim, self-chunk}) ----
    char* w = (char*)d_ws;
    auto alloc = [&](long bytes) { char* p = w; w += (bytes + 255) & ~255L; return p; };
    ushort* xfT     = (ushort*)alloc(2L * B * NXP * C);        // [B][1024][256]
    ushort* xqT     = (ushort*)alloc(2L * B * NXP * C);        // [B][1024][256]
    ushort* concatT = (ushort*)alloc(2L * B * NXP * C3);       // [B][1024][768]
    ushort* gate_cn = (ushort*)alloc(2L * B * C * NXP);        // [B][256][1024]
    ushort* Wq_bf   = (ushort*)alloc(2L * C * C);
    ushort* Ws_bf   = (ushort*)alloc(2L * C * C);
    ushort* Wg_bf   = (ushort*)alloc(2L * C * C);
    ushort* Wfi_bf  = (ushort*)alloc(2L * O * C3);
    char* ub = w;                                              // union base
    // sim-phase region (dead before first self-chunk write):
    ushort* zfT   = (ushort*)ub;                               // [B][128][256]
    ushort* zsT   = zfT + (long)B * NZP * C;                   // [B][128][256]
    ushort* zg_cn = zsT + (long)B * NZP * C;                   // [B][256][128]
    float*  Ssim  = (float*)(zg_cn + (long)B * C * NZP);       // [B][1024][128]
    ushort* Psim  = (ushort*)(Ssim + (long)B * NXP * NZP);     // [B][1024][64]
    // self-phase region (same base):
    float*  Schunk = (float*)ub;                               // [8][1024][1024]
    ushort* Pchunk = (ushort*)(Schunk + (long)BCH * NXP * NXP);// [8][1024][1024]

    // ---- 0) convert weights, transpose+convert activations ----
    cvt_bf<<<dim3((C * C + 255) / 256), 256, 0, stream>>>(Wq, Wq_bf, C * C);
    cvt_bf<<<dim3((C * C + 255) / 256), 256, 0, stream>>>(Ws, Ws_bf, C * C);
    cvt_bf<<<dim3((C * C + 255) / 256), 256, 0, stream>>>(Wg, Wg_bf, C * C);
    cvt_bf<<<dim3((O * C3 + 255) / 256), 256, 0, stream>>>(Wfi, Wfi_bf, O * C3);
    transpose_cvt<<<dim3(C / 32, NXP / 32, B), 256, 0, stream>>>(xf, xfT, C, NX, NXP);
    transpose_cvt<<<dim3(C / 32, NZP / 32, B), 256, 0, stream>>>(zf, zfT, C, NZ, NZP);

    // ---- 1) conv q: xqT[n][c] = xfT[n][:]·Wq[c][:] + bq[c] ----
    mfma_nt<1, true, true><<<dim3(2, 8, B), 256, 0, stream>>>(
        xfT, (long)NXP * C, C, Wq_bf, 0, C,
        xqT, (long)NXP * C, C, C, C, bq, nullptr, nullptr, nullptr, nullptr);

    // ---- 2) conv g -> concatT section 2 (gateT[n][c]) ----
    mfma_nt<2, true, true><<<dim3(2, 8, B), 256, 0, stream>>>(
        xfT, (long)NXP * C, C, Wg_bf, 0, C,
        concatT + 2 * C, (long)NXP * C3, C3, C, C, bg, g_gamma, g_beta, g_mean, g_var);

    // ---- 3) gate other orientation: gate_cn[c][n] (A'=Wg, B'=xfT) ----
    mfma_nt<2, false, true><<<dim3(8, 2, B), 256, 0, stream>>>(
        Wg_bf, 0, C, xfT, (long)NXP * C, C,
        gate_cn, (long)C * NXP, NXP, NXP, C, bg, g_gamma, g_beta, g_mean, g_var);

    // ---- 4) conv zs: zsT[m][c] ----
    mfma_nt<1, true, true><<<dim3(2, 1, B), 256, 0, stream>>>(
        zfT, (long)NZP * C, C, Ws_bf, 0, C,
        zsT, (long)NZP * C, C, C, C, bs, nullptr, nullptr, nullptr, nullptr);

    // ---- 5) zg other orientation: zg_cn[c][m] ----
    mfma_nt<2, false, true><<<dim3(1, 2, B), 256, 0, stream>>>(
        Wg_bf, 0, C, zfT, (long)NZP * C, C,
        zg_cn, (long)C * NZP, NZP, NZP, C, bg, g_gamma, g_beta, g_mean, g_var);

    // ---- 6) sim scores: Ssim[n][m] = xqT[n][:]·zsT[m][:] ----
    mfma_nt<0, true, false><<<dim3(1, 8, B), 256, 0, stream>>>(
        xqT, (long)NXP * C, C, zsT, (long)NZP * C, C,
        Ssim, (long)NXP * NZP, NZP, NZP, C, nullptr, nullptr, nullptr, nullptr, nullptr);

    // ---- 7) sim softmax -> Psim bf16 (pad cols zeroed) ----
    softmax_sim<<<dim3(NX, B), 64, 0, stream>>>(Ssim, Psim);

    // ---- 8) sim PV: embT[n][c] = Psim[n][:]·zg_cn[c][:] -> concatT sec 0 ----
    mfma_nt<0, true, true><<<dim3(2, 8, B), 256, 0, stream>>>(
        Psim, (long)NXP * 64, 64, zg_cn, (long)C * NZP, NZP,
        concatT, (long)NXP * C3, C3, C, 64, nullptr, nullptr, nullptr, nullptr, nullptr);

    // ---- 9) self-attention, chunked over batches ----
    for (int ch = 0; ch < B / BCH; ++ch) {
        const long ab = (long)ch * BCH;
        // scores: Schunk[n][m] = xqT[n][:]·xqT[m][:]
        mfma_nt<0, true, false><<<dim3(8, 8, BCH), 256, 0, stream>>>(
            xqT + ab * NXP * C, (long)NXP * C, C,
            xqT + ab * NXP * C, (long)NXP * C, C,
            Schunk, (long)NXP * NXP, NXP, NXP, C, nullptr, nullptr, nullptr, nullptr, nullptr);
        softmax_self<<<dim3(NX, BCH), 256, 0, stream>>>(Schunk, Pchunk);
        // PV: self_embT[n][c] = Pchunk[n][:]·gate_cn[c][:] -> concatT sec 1
        mfma_nt<0, true, true><<<dim3(2, 8, BCH), 256, 0, stream>>>(
            Pchunk, (long)NXP * NXP, NXP,
            gate_cn + ab * C * NXP, (long)C * NXP, NXP,
            concatT + C + ab * NXP * C3, (long)NXP * C3, C3, C, NXP,
            nullptr, nullptr, nullptr, nullptr, nullptr);
    }

    // ---- 10) final conv: out[o][n] = relu(bn(Wfi[o][:]·concatT[n][:] + bfi)) ----
    mfma_nt<2, false, false><<<dim3(8, 2, B), 256, 0, stream>>>(
        Wfi_bf, 0, C3, concatT, (long)NXP * C3, C3,
        out, (long)O * NX, NX, NX, C3, bfi, fi_gamma, fi_beta, fi_mean, fi_var);
}